// Round 7
// baseline (94.655 us; speedup 1.0000x reference)
//
#include <hip/hip_runtime.h>
#include <stdint.h>

// ---------------------------------------------------------------------------
// NeighborSearch: data[n,3], queries[m,3], radius scalar.
// Out layout (int32): [0, m*n)   neighbors_index (compacted front, -1 pad)
//                     [m*n, m*n+m+1) row_splits (exclusive prefix of counts)
//
// Fast path (n==m==8192), 4 launches:
//   K0 init: qpack[q] = (qx,qy,qz,q2), counts[q] = 0.
//   K1 count_flip: wave = 64 data points in REGISTERS (lane=point), loop 128
//      queries broadcast via s_load (readfirstlane-forced uniform index).
//      ballot(u<=T) IS the per-(query,chunk) mask -> parked per lane, stored
//      chunk-major coalesced; counts via deterministic atomicAdd.
//      (R6 lesson: LDS-staged counting costs ~40us -- 1.05M ds_read_b128 is
//      a 20us floor by itself. Flipped orientation needs no LDS at all.)
//   K2 scan: exclusive prefix -> row_splits.
//   K3 fill_emit: emit from masks into [0,L); -1 int4 stream over [Lr, m*n).
// ---------------------------------------------------------------------------

#define N8 8192

__device__ __forceinline__ float next_up(float x) {
    return __uint_as_float(__float_as_uint(x) + 1u);
}
__device__ __forceinline__ float next_down(float x) {
    return __uint_as_float(__float_as_uint(x) - 1u);
}

// Largest float T such that correctly-rounded sqrt(T) <= r (r > 0).
// (u <= T) <=> (sqrt_rn(max(u,0)) <= r), since sqrt_rn is monotone.
__device__ __forceinline__ float sq_threshold(float r) {
    float T = __fmul_rn(r, r);
    while (__fsqrt_rn(T) > r) T = next_down(T);
    while (__fsqrt_rn(next_up(T)) <= r) T = next_up(T);
    return T;
}

// Reference arithmetic, exactly (no contraction):
// d2 = (dx*dx + dy*dy) + dz*dz ; dot = fma(qz,dz, fma(qy,dy, qx*dx))
// u  = (q2 + d2) - 2*dot
__device__ __forceinline__ float pair_metric(float qx, float qy, float qz, float q2,
                                             float dx, float dy, float dz) {
    float d2 = __fadd_rn(__fadd_rn(__fmul_rn(dx, dx), __fmul_rn(dy, dy)),
                         __fmul_rn(dz, dz));
    float dot = __builtin_fmaf(qz, dz, __builtin_fmaf(qy, dy, __fmul_rn(qx, dx)));
    return __fsub_rn(__fadd_rn(q2, d2), __fmul_rn(2.0f, dot));
}

// ========================= fast path (8192 x 8192) =========================

// 32 blocks x 256: pack query coords + exact q2; zero counts.
__global__ __launch_bounds__(256) void init_qpack(
    const float* __restrict__ queries, float4* __restrict__ qpack,
    int* __restrict__ counts) {
    int q = blockIdx.x * 256 + threadIdx.x;
    if (q < N8) {
        float qx = queries[3 * q + 0], qy = queries[3 * q + 1], qz = queries[3 * q + 2];
        float q2 = __fadd_rn(__fadd_rn(__fmul_rn(qx, qx), __fmul_rn(qy, qy)),
                             __fmul_rn(qz, qz));
        qpack[q] = make_float4(qx, qy, qz, q2);
        counts[q] = 0;
    }
}

// Grid: 2048 x 256 = 8192 waves. Wave w: chunk c = w>>6 (64 points in regs,
// lane = point c*64+lane), query group g = w&63 (queries [g*128, g*128+128)).
// masks2[c*8192+q] = 64-bit mask over points [c*64,(c+1)*64) for query q.
__global__ __launch_bounds__(256) void count_flip(
    const float* __restrict__ data, const float4* __restrict__ qpack,
    const float* __restrict__ radius_p,
    unsigned long long* __restrict__ masks2, int* __restrict__ counts) {
    int lane = threadIdx.x & 63;
    int w = blockIdx.x * 4 + (threadIdx.x >> 6);
    int c = w >> 6;
    int g = w & 63;

    float T = sq_threshold(radius_p[0]);

    int p = c * 64 + lane;
    float dx = data[3 * p + 0], dy = data[3 * p + 1], dz = data[3 * p + 2];
    float d2 = __fadd_rn(__fadd_rn(__fmul_rn(dx, dx), __fmul_rn(dy, dy)),
                         __fmul_rn(dz, dz));

    for (int s = 0; s < 2; ++s) {
        int qbase = g * 128 + s * 64;
        unsigned long long parked = 0;
#pragma unroll 4
        for (int j = 0; j < 64; ++j) {
            // force wave-uniform index -> s_load_dwordx4 broadcast
            int jj = __builtin_amdgcn_readfirstlane(qbase + j);
            float4 Q = qpack[jj];
            float dot = __builtin_fmaf(Q.z, dz,
                          __builtin_fmaf(Q.y, dy, __fmul_rn(Q.x, dx)));
            float u = __fsub_rn(__fadd_rn(Q.w, d2), __fmul_rn(2.0f, dot));
            unsigned long long mk = __ballot(u <= T);
            if (lane == j) parked = mk;   // lane j keeps query qbase+j's mask
        }
        masks2[(size_t)c * N8 + qbase + lane] = parked;   // coalesced 512B
        atomicAdd(&counts[qbase + lane], __popcll(parked));
    }
}

// Exclusive scan of counts[0..m) -> rs[0..m]. One block, m <= 8192.
__global__ __launch_bounds__(1024) void scan_kernel2(const int* __restrict__ counts,
                                                     int* __restrict__ rs, int m) {
    __shared__ int part[1024];
    int t = threadIdx.x;
    int base = t * 8;
    int c[8];
    int s = 0;
    for (int k = 0; k < 8; ++k) {
        int p = base + k;
        c[k] = (p < m) ? counts[p] : 0;
        s += c[k];
    }
    part[t] = s;
    __syncthreads();
    for (int off = 1; off < 1024; off <<= 1) {
        int v = 0;
        if (t >= off) v = part[t - off];
        __syncthreads();
        if (t >= off) part[t] += v;
        __syncthreads();
    }
    int run = (t == 0) ? 0 : part[t - 1];
    for (int k = 0; k < 8; ++k) {
        int p = base + k;
        if (p < m) rs[p] = run;
        run += c[k];
    }
    if (t == 1023) rs[m] = part[1023];
}

// Grid: 2048 x 256. Wave w of block b emits query q = b*4+w into [0,L);
// then all threads grid-stride -1 over [Lr, 64M). Disjoint writes.
// Masks are chunk-major: lane l reads chunks l and 64+l for its query.
__global__ __launch_bounds__(256) void fill_emit(
    const unsigned long long* __restrict__ masks2, const int* __restrict__ rs,
    int* __restrict__ out_idx) {
    int wave = threadIdx.x >> 6;
    int lane = threadIdx.x & 63;
    int q = blockIdx.x * 4 + wave;

    // ---- emit (positions < L) ----
    unsigned long long lo = masks2[(size_t)lane * N8 + q];
    unsigned long long hi = masks2[(size_t)(64 + lane) * N8 + q];
    int plo = __popcll(lo), phi = __popcll(hi);
    int ilo = plo, ihi = phi;
    for (int off = 1; off < 64; off <<= 1) {
        int a = __shfl_up(ilo, off, 64);
        int b = __shfl_up(ihi, off, 64);
        if (lane >= off) { ilo += a; ihi += b; }
    }
    int total_lo = __shfl(ilo, 63, 64);
    int base = rs[q];
    int pos_lo = base + ilo - plo;
    int pos_hi = base + total_lo + ihi - phi;
    int jb_lo = lane * 64, jb_hi = (64 + lane) * 64;
    while (lo) {
        int b = __builtin_ctzll(lo);
        out_idx[pos_lo++] = jb_lo + b;
        lo &= lo - 1;
    }
    while (hi) {
        int b = __builtin_ctzll(hi);
        out_idx[pos_hi++] = jb_hi + b;
        hi &= hi - 1;
    }

    // ---- fill (positions >= L) ----
    int L = rs[N8];                       // uniform load, L2-hot
    int Lr = (L + 3) & ~3;                // int4-align the fill start
    if (blockIdx.x == 0 && (int)threadIdx.x < (Lr - L))
        out_idx[L + threadIdx.x] = -1;
    int4* out4 = (int4*)out_idx;
    const int4 v = make_int4(-1, -1, -1, -1);
    const size_t n4 = (size_t)N8 * N8 / 4;       // 16,777,216
    size_t i = (size_t)(Lr >> 2) + (size_t)blockIdx.x * 256 + threadIdx.x;
    const size_t stride = 2048ull * 256ull;
    for (; i < n4; i += stride) out4[i] = v;
}

// ====================== generic fallback (round-1 path) ======================

__global__ __launch_bounds__(256) void fill_kernel(int* __restrict__ out, size_t total) {
    size_t n4 = total >> 2;
    int4* out4 = (int4*)out;
    size_t i = (size_t)blockIdx.x * blockDim.x + threadIdx.x;
    size_t stride = (size_t)gridDim.x * blockDim.x;
    const int4 v = make_int4(-1, -1, -1, -1);
    for (; i < n4; i += stride) out4[i] = v;
    if (blockIdx.x == 0 && threadIdx.x == 0) {
        for (size_t k = n4 << 2; k < total; ++k) out[k] = -1;
    }
}

__global__ __launch_bounds__(256) void count_kernel(
    const float* __restrict__ data, const float* __restrict__ queries,
    const float* __restrict__ radius_p, int n, int m, int* __restrict__ counts) {
    int q = (blockIdx.x * blockDim.x + threadIdx.x) >> 6;
    int lane = threadIdx.x & 63;
    if (q >= m) return;
    float r = radius_p[0];
    float T = sq_threshold(r);
    float qx = queries[3 * q + 0], qy = queries[3 * q + 1], qz = queries[3 * q + 2];
    float q2 = __fadd_rn(__fadd_rn(__fmul_rn(qx, qx), __fmul_rn(qy, qy)),
                         __fmul_rn(qz, qz));
    int cnt = 0;
    for (int j = lane; j < n; j += 64) {
        float u = pair_metric(qx, qy, qz, q2, data[3 * j], data[3 * j + 1], data[3 * j + 2]);
        if (u <= T) cnt++;
    }
    for (int off = 32; off > 0; off >>= 1) cnt += __shfl_down(cnt, off, 64);
    if (lane == 0) counts[q] = cnt;
}

__global__ __launch_bounds__(256) void emit_kernel(
    const float* __restrict__ data, const float* __restrict__ queries,
    const float* __restrict__ radius_p, int n, int m,
    const int* __restrict__ row_splits, int* __restrict__ out_idx) {
    int q = (blockIdx.x * blockDim.x + threadIdx.x) >> 6;
    int lane = threadIdx.x & 63;
    if (q >= m) return;
    float r = radius_p[0];
    float T = sq_threshold(r);
    float qx = queries[3 * q + 0], qy = queries[3 * q + 1], qz = queries[3 * q + 2];
    float q2 = __fadd_rn(__fadd_rn(__fmul_rn(qx, qx), __fmul_rn(qy, qy)),
                         __fmul_rn(qz, qz));
    int base = row_splits[q];
    unsigned long long lane_mask_lt = (lane == 0) ? 0ULL : (~0ULL >> (64 - lane));
    for (int j0 = 0; j0 < n; j0 += 64) {
        int j = j0 + lane;
        bool pred = false;
        if (j < n) {
            float u = pair_metric(qx, qy, qz, q2, data[3 * j], data[3 * j + 1], data[3 * j + 2]);
            pred = (u <= T);
        }
        unsigned long long mask = __ballot(pred);
        if (pred) {
            int pos = base + __popcll(mask & lane_mask_lt);
            out_idx[pos] = j;
        }
        base += __popcll(mask);
    }
}

// ===========================================================================

extern "C" void kernel_launch(void* const* d_in, const int* in_sizes, int n_in,
                              void* d_out, int out_size, void* d_ws, size_t ws_size,
                              hipStream_t stream) {
    const float* data = (const float*)d_in[0];
    const float* queries = (const float*)d_in[1];
    const float* radius = (const float*)d_in[2];
    int n = in_sizes[0] / 3;
    int m = in_sizes[1] / 3;
    int* out = (int*)d_out;
    size_t idx_count = (size_t)m * (size_t)n;
    int* row = out + idx_count;  // m+1 ints

    // ws layout: masks2 (8MB) | counts (32KB) | qpack (128KB)
    size_t mask_bytes = (size_t)N8 * 128 * 8;
    size_t need = mask_bytes + N8 * 4 + N8 * 16;
    bool fast = (n == N8) && (m == N8) && (ws_size >= need);

    if (fast) {
        unsigned long long* masks2 = (unsigned long long*)d_ws;
        int* counts = (int*)((char*)d_ws + mask_bytes);
        float4* qpack = (float4*)((char*)d_ws + mask_bytes + N8 * 4);
        init_qpack<<<32, 256, 0, stream>>>(queries, qpack, counts);
        count_flip<<<2048, 256, 0, stream>>>(data, qpack, radius, masks2, counts);
        scan_kernel2<<<1, 1024, 0, stream>>>(counts, row, m);
        fill_emit<<<2048, 256, 0, stream>>>(masks2, row, out);
    } else {
        fill_kernel<<<2048, 256, 0, stream>>>(out, idx_count);
        int blocks = (m * 64 + 255) / 256;
        count_kernel<<<blocks, 256, 0, stream>>>(data, queries, radius, n, m, row);
        scan_kernel2<<<1, 1024, 0, stream>>>(row, row, m);
        emit_kernel<<<blocks, 256, 0, stream>>>(data, queries, radius, n, m, row, out);
    }
}

// Round 8
// 90.979 us; speedup vs baseline: 1.0404x; 1.0404x over previous
//
#include <hip/hip_runtime.h>
#include <stdint.h>

// ---------------------------------------------------------------------------
// NeighborSearch: data[n,3], queries[m,3], radius scalar.
// Out layout (int32): [0, m*n)   neighbors_index (compacted front, -1 pad)
//                     [m*n, m*n+m+1) row_splits (exclusive prefix of counts)
//
// Fast path (n==m==8192), 4 launches:
//   K0 init: qpack[q] = (qx,qy,qz,q2), counts[q] = 0.
//   K1 count_flip: wave = 64 data points in REGISTERS (lane=point), loop 128
//      queries via s_load broadcast. ballot(u<=T) IS the (query,chunk) mask.
//      Masks stored QUERY-MAJOR (scattered 8B @1KB stride) so K3's reads are
//      coalesced -- the transpose cost hides under K1's VALU work.
//      (R7 lesson: chunk-major masks made fill_emit's reads 64-line scatter,
//       +30us at the head of the write stream.)
//   K2 scan: exclusive prefix -> row_splits.
//   K3 fill_emit: VERBATIM R6 kernel (proven): emit from query-major masks
//      into [0,L); -1 int4 stream over [Lr, m*n).
// ---------------------------------------------------------------------------

#define N8 8192

__device__ __forceinline__ float next_up(float x) {
    return __uint_as_float(__float_as_uint(x) + 1u);
}
__device__ __forceinline__ float next_down(float x) {
    return __uint_as_float(__float_as_uint(x) - 1u);
}

// Largest float T such that correctly-rounded sqrt(T) <= r (r > 0).
// (u <= T) <=> (sqrt_rn(max(u,0)) <= r), since sqrt_rn is monotone.
__device__ __forceinline__ float sq_threshold(float r) {
    float T = __fmul_rn(r, r);
    while (__fsqrt_rn(T) > r) T = next_down(T);
    while (__fsqrt_rn(next_up(T)) <= r) T = next_up(T);
    return T;
}

// Reference arithmetic, exactly (no contraction):
// d2 = (dx*dx + dy*dy) + dz*dz ; dot = fma(qz,dz, fma(qy,dy, qx*dx))
// u  = (q2 + d2) - 2*dot
__device__ __forceinline__ float pair_metric(float qx, float qy, float qz, float q2,
                                             float dx, float dy, float dz) {
    float d2 = __fadd_rn(__fadd_rn(__fmul_rn(dx, dx), __fmul_rn(dy, dy)),
                         __fmul_rn(dz, dz));
    float dot = __builtin_fmaf(qz, dz, __builtin_fmaf(qy, dy, __fmul_rn(qx, dx)));
    return __fsub_rn(__fadd_rn(q2, d2), __fmul_rn(2.0f, dot));
}

// ========================= fast path (8192 x 8192) =========================

// 32 blocks x 256: pack query coords + exact q2; zero counts.
__global__ __launch_bounds__(256) void init_qpack(
    const float* __restrict__ queries, float4* __restrict__ qpack,
    int* __restrict__ counts) {
    int q = blockIdx.x * 256 + threadIdx.x;
    if (q < N8) {
        float qx = queries[3 * q + 0], qy = queries[3 * q + 1], qz = queries[3 * q + 2];
        float q2 = __fadd_rn(__fadd_rn(__fmul_rn(qx, qx), __fmul_rn(qy, qy)),
                             __fmul_rn(qz, qz));
        qpack[q] = make_float4(qx, qy, qz, q2);
        counts[q] = 0;
    }
}

// Grid: 2048 x 256 = 8192 waves. Wave w: chunk c = w>>6 (64 points in regs,
// lane = point c*64+lane), query group g = w&63 (queries [g*128, g*128+128)).
// masks[q*128 + c] = 64-bit mask over points [c*64,(c+1)*64) for query q.
__global__ __launch_bounds__(256) void count_flip(
    const float* __restrict__ data, const float4* __restrict__ qpack,
    const float* __restrict__ radius_p,
    unsigned long long* __restrict__ masks, int* __restrict__ counts) {
    int lane = threadIdx.x & 63;
    int w = blockIdx.x * 4 + (threadIdx.x >> 6);
    int c = w >> 6;
    int g = w & 63;

    float T = sq_threshold(radius_p[0]);

    int p = c * 64 + lane;
    float dx = data[3 * p + 0], dy = data[3 * p + 1], dz = data[3 * p + 2];
    float d2 = __fadd_rn(__fadd_rn(__fmul_rn(dx, dx), __fmul_rn(dy, dy)),
                         __fmul_rn(dz, dz));

    for (int s = 0; s < 2; ++s) {
        int qbase = g * 128 + s * 64;
        unsigned long long parked = 0;
#pragma unroll 4
        for (int j = 0; j < 64; ++j) {
            // force wave-uniform index -> s_load_dwordx4 broadcast
            int jj = __builtin_amdgcn_readfirstlane(qbase + j);
            float4 Q = qpack[jj];
            float dot = __builtin_fmaf(Q.z, dz,
                          __builtin_fmaf(Q.y, dy, __fmul_rn(Q.x, dx)));
            float u = __fsub_rn(__fadd_rn(Q.w, d2), __fmul_rn(2.0f, dot));
            unsigned long long mk = __ballot(u <= T);
            if (lane == j) parked = mk;   // lane j keeps query qbase+j's mask
        }
        // QUERY-MAJOR store: lane l -> query qbase+l, chunk c (1KB stride)
        masks[((size_t)(qbase + lane)) * 128 + c] = parked;
        atomicAdd(&counts[qbase + lane], __popcll(parked));
    }
}

// Exclusive scan of counts[0..m) -> rs[0..m]. One block, m <= 8192.
__global__ __launch_bounds__(1024) void scan_kernel2(const int* __restrict__ counts,
                                                     int* __restrict__ rs, int m) {
    __shared__ int part[1024];
    int t = threadIdx.x;
    int base = t * 8;
    int c[8];
    int s = 0;
    for (int k = 0; k < 8; ++k) {
        int p = base + k;
        c[k] = (p < m) ? counts[p] : 0;
        s += c[k];
    }
    part[t] = s;
    __syncthreads();
    for (int off = 1; off < 1024; off <<= 1) {
        int v = 0;
        if (t >= off) v = part[t - off];
        __syncthreads();
        if (t >= off) part[t] += v;
        __syncthreads();
    }
    int run = (t == 0) ? 0 : part[t - 1];
    for (int k = 0; k < 8; ++k) {
        int p = base + k;
        if (p < m) rs[p] = run;
        run += c[k];
    }
    if (t == 1023) rs[m] = part[1023];
}

// Grid: 2048 x 256. VERBATIM R6 fill_emit (query-major masks, proven).
// Wave w of block b emits query q = b*4+w into [0,L); then all threads
// grid-stride -1 over [Lr, 64M). Disjoint writes.
__global__ __launch_bounds__(256) void fill_emit(
    const unsigned long long* __restrict__ masks, const int* __restrict__ rs,
    int* __restrict__ out_idx) {
    int wave = threadIdx.x >> 6;
    int lane = threadIdx.x & 63;
    int q = blockIdx.x * 4 + wave;

    // ---- emit (positions < L) ----
    unsigned long long lo = masks[(size_t)q * 128 + lane];
    unsigned long long hi = masks[(size_t)q * 128 + 64 + lane];
    int plo = __popcll(lo), phi = __popcll(hi);
    int ilo = plo, ihi = phi;
    for (int off = 1; off < 64; off <<= 1) {
        int a = __shfl_up(ilo, off, 64);
        int b = __shfl_up(ihi, off, 64);
        if (lane >= off) { ilo += a; ihi += b; }
    }
    int total_lo = __shfl(ilo, 63, 64);
    int base = rs[q];
    int pos_lo = base + ilo - plo;
    int pos_hi = base + total_lo + ihi - phi;
    int jb_lo = lane * 64, jb_hi = (64 + lane) * 64;
    while (lo) {
        int b = __builtin_ctzll(lo);
        out_idx[pos_lo++] = jb_lo + b;
        lo &= lo - 1;
    }
    while (hi) {
        int b = __builtin_ctzll(hi);
        out_idx[pos_hi++] = jb_hi + b;
        hi &= hi - 1;
    }

    // ---- fill (positions >= L) ----
    int L = rs[N8];                       // uniform load, L2-hot
    int Lr = (L + 3) & ~3;                // int4-align the fill start
    if (blockIdx.x == 0 && (int)threadIdx.x < (Lr - L))
        out_idx[L + threadIdx.x] = -1;
    int4* out4 = (int4*)out_idx;
    const int4 v = make_int4(-1, -1, -1, -1);
    const size_t n4 = (size_t)N8 * N8 / 4;       // 16,777,216
    size_t i = (size_t)(Lr >> 2) + (size_t)blockIdx.x * 256 + threadIdx.x;
    const size_t stride = 2048ull * 256ull;
    for (; i < n4; i += stride) out4[i] = v;
}

// ====================== generic fallback (round-1 path) ======================

__global__ __launch_bounds__(256) void fill_kernel(int* __restrict__ out, size_t total) {
    size_t n4 = total >> 2;
    int4* out4 = (int4*)out;
    size_t i = (size_t)blockIdx.x * blockDim.x + threadIdx.x;
    size_t stride = (size_t)gridDim.x * blockDim.x;
    const int4 v = make_int4(-1, -1, -1, -1);
    for (; i < n4; i += stride) out4[i] = v;
    if (blockIdx.x == 0 && threadIdx.x == 0) {
        for (size_t k = n4 << 2; k < total; ++k) out[k] = -1;
    }
}

__global__ __launch_bounds__(256) void count_kernel(
    const float* __restrict__ data, const float* __restrict__ queries,
    const float* __restrict__ radius_p, int n, int m, int* __restrict__ counts) {
    int q = (blockIdx.x * blockDim.x + threadIdx.x) >> 6;
    int lane = threadIdx.x & 63;
    if (q >= m) return;
    float r = radius_p[0];
    float T = sq_threshold(r);
    float qx = queries[3 * q + 0], qy = queries[3 * q + 1], qz = queries[3 * q + 2];
    float q2 = __fadd_rn(__fadd_rn(__fmul_rn(qx, qx), __fmul_rn(qy, qy)),
                         __fmul_rn(qz, qz));
    int cnt = 0;
    for (int j = lane; j < n; j += 64) {
        float u = pair_metric(qx, qy, qz, q2, data[3 * j], data[3 * j + 1], data[3 * j + 2]);
        if (u <= T) cnt++;
    }
    for (int off = 32; off > 0; off >>= 1) cnt += __shfl_down(cnt, off, 64);
    if (lane == 0) counts[q] = cnt;
}

__global__ __launch_bounds__(256) void emit_kernel(
    const float* __restrict__ data, const float* __restrict__ queries,
    const float* __restrict__ radius_p, int n, int m,
    const int* __restrict__ row_splits, int* __restrict__ out_idx) {
    int q = (blockIdx.x * blockDim.x + threadIdx.x) >> 6;
    int lane = threadIdx.x & 63;
    if (q >= m) return;
    float r = radius_p[0];
    float T = sq_threshold(r);
    float qx = queries[3 * q + 0], qy = queries[3 * q + 1], qz = queries[3 * q + 2];
    float q2 = __fadd_rn(__fadd_rn(__fmul_rn(qx, qx), __fmul_rn(qy, qy)),
                         __fmul_rn(qz, qz));
    int base = row_splits[q];
    unsigned long long lane_mask_lt = (lane == 0) ? 0ULL : (~0ULL >> (64 - lane));
    for (int j0 = 0; j0 < n; j0 += 64) {
        int j = j0 + lane;
        bool pred = false;
        if (j < n) {
            float u = pair_metric(qx, qy, qz, q2, data[3 * j], data[3 * j + 1], data[3 * j + 2]);
            pred = (u <= T);
        }
        unsigned long long mask = __ballot(pred);
        if (pred) {
            int pos = base + __popcll(mask & lane_mask_lt);
            out_idx[pos] = j;
        }
        base += __popcll(mask);
    }
}

// ===========================================================================

extern "C" void kernel_launch(void* const* d_in, const int* in_sizes, int n_in,
                              void* d_out, int out_size, void* d_ws, size_t ws_size,
                              hipStream_t stream) {
    const float* data = (const float*)d_in[0];
    const float* queries = (const float*)d_in[1];
    const float* radius = (const float*)d_in[2];
    int n = in_sizes[0] / 3;
    int m = in_sizes[1] / 3;
    int* out = (int*)d_out;
    size_t idx_count = (size_t)m * (size_t)n;
    int* row = out + idx_count;  // m+1 ints

    // ws layout: masks (8MB, query-major) | counts (32KB) | qpack (128KB)
    size_t mask_bytes = (size_t)N8 * 128 * 8;
    size_t need = mask_bytes + N8 * 4 + N8 * 16;
    bool fast = (n == N8) && (m == N8) && (ws_size >= need);

    if (fast) {
        unsigned long long* masks = (unsigned long long*)d_ws;
        int* counts = (int*)((char*)d_ws + mask_bytes);
        float4* qpack = (float4*)((char*)d_ws + mask_bytes + N8 * 4);
        init_qpack<<<32, 256, 0, stream>>>(queries, qpack, counts);
        count_flip<<<2048, 256, 0, stream>>>(data, qpack, radius, masks, counts);
        scan_kernel2<<<1, 1024, 0, stream>>>(counts, row, m);
        fill_emit<<<2048, 256, 0, stream>>>(masks, row, out);
    } else {
        fill_kernel<<<2048, 256, 0, stream>>>(out, idx_count);
        int blocks = (m * 64 + 255) / 256;
        count_kernel<<<blocks, 256, 0, stream>>>(data, queries, radius, n, m, row);
        scan_kernel2<<<1, 1024, 0, stream>>>(row, row, m);
        emit_kernel<<<blocks, 256, 0, stream>>>(data, queries, radius, n, m, row, out);
    }
}

// Round 9
// 85.318 us; speedup vs baseline: 1.1094x; 1.0664x over previous
//
#include <hip/hip_runtime.h>
#include <stdint.h>

// ---------------------------------------------------------------------------
// NeighborSearch: data[n,3], queries[m,3], radius scalar.
// Out layout (int32): [0, m*n)   neighbors_index (compacted front, -1 pad)
//                     [m*n, m*n+m+1) row_splits (exclusive prefix of counts)
//
// Fast path (n==m==8192):
//   memset: counts = 0 (32KB, hipMemsetAsync -- graph-capturable).
//   K1 fused_fill_count (2048x256, role = bid&1):
//     fill half: -1 int4 stream over [C0, 64M), C0 = 2M ints (242 MB).
//     count half: wave = 64 data points in regs; queries broadcast via
//       v_readlane (NO memory ops in inner loop -- R8's s_load chain stalled).
//       ballot(u<=T) is the (query,chunk) mask; parked per lane; stored
//       query-major; counts via atomicAdd (proven R8).
//     The two roles overlap on every CU: VALU pipe (count) under store BW
//     (fill), per m114 MFMA/VALU-style co-scheduling.
//   K2 scan (verbatim proven): counts -> row_splits.
//   K3 emit_fill_tail: R6-verbatim emit of [0,L) + tail fill [L, C0) only.
//     Safe for any L: runs after K1 in stream order.
// ---------------------------------------------------------------------------

#define N8 8192
#define C0 2097152  // fill boundary in ints (8 MB); emit region is far below

__device__ __forceinline__ float next_up(float x) {
    return __uint_as_float(__float_as_uint(x) + 1u);
}
__device__ __forceinline__ float next_down(float x) {
    return __uint_as_float(__float_as_uint(x) - 1u);
}

// Largest float T such that correctly-rounded sqrt(T) <= r (r > 0).
// (u <= T) <=> (sqrt_rn(max(u,0)) <= r), since sqrt_rn is monotone.
__device__ __forceinline__ float sq_threshold(float r) {
    float T = __fmul_rn(r, r);
    while (__fsqrt_rn(T) > r) T = next_down(T);
    while (__fsqrt_rn(next_up(T)) <= r) T = next_up(T);
    return T;
}

// Reference arithmetic, exactly (no contraction):
// d2 = (dx*dx + dy*dy) + dz*dz ; dot = fma(qz,dz, fma(qy,dy, qx*dx))
// u  = (q2 + d2) - 2*dot
__device__ __forceinline__ float pair_metric(float qx, float qy, float qz, float q2,
                                             float dx, float dy, float dz) {
    float d2 = __fadd_rn(__fadd_rn(__fmul_rn(dx, dx), __fmul_rn(dy, dy)),
                         __fmul_rn(dz, dz));
    float dot = __builtin_fmaf(qz, dz, __builtin_fmaf(qy, dy, __fmul_rn(qx, dx)));
    return __fsub_rn(__fadd_rn(q2, d2), __fmul_rn(2.0f, dot));
}

__device__ __forceinline__ float bc_lane(float x, int j) {
    return __int_as_float(__builtin_amdgcn_readlane(__float_as_int(x), j));
}

// ========================= fast path (8192 x 8192) =========================

// Grid: 2048 x 256. Odd blocks: fill [C0, 64M). Even blocks: count.
// Count role: block rb=bid>>1 in [0,1024); wave wv handles units
// u = half*4096 + rb*4 + wv for half in {0,1}; unit u -> chunk c=u>>6,
// query group g=u&63 (queries [g*128,(g+1)*128)).
__global__ __launch_bounds__(256) void fused_fill_count(
    const float* __restrict__ data, const float* __restrict__ queries,
    const float* __restrict__ radius_p, int* __restrict__ out_idx,
    unsigned long long* __restrict__ masks, int* __restrict__ counts) {
    int bid = blockIdx.x;
    int lane = threadIdx.x & 63;
    int wv = threadIdx.x >> 6;
    int rb = bid >> 1;

    if (bid & 1) {
        // ---- fill role: -1 over [C0, 64M) ----
        int4* out4 = (int4*)out_idx;
        const int4 v = make_int4(-1, -1, -1, -1);
        const size_t n4 = (size_t)N8 * N8 / 4;
        size_t i = (size_t)(C0 / 4) + (size_t)rb * 256 + threadIdx.x;
        const size_t stride = 1024ull * 256ull;
        for (; i < n4; i += stride) out4[i] = v;
        return;
    }

    // ---- count role ----
    float T = sq_threshold(radius_p[0]);
    for (int half = 0; half < 2; ++half) {
        int u = half * 4096 + rb * 4 + wv;
        int c = u >> 6;
        int g = u & 63;
        int p = c * 64 + lane;
        float dx = data[3 * p + 0], dy = data[3 * p + 1], dz = data[3 * p + 2];
        float d2 = __fadd_rn(__fadd_rn(__fmul_rn(dx, dx), __fmul_rn(dy, dy)),
                             __fmul_rn(dz, dz));
        for (int s = 0; s < 2; ++s) {
            int qbase = g * 128 + s * 64;
            int q = qbase + lane;
            float qx = queries[3 * q + 0], qy = queries[3 * q + 1],
                  qz = queries[3 * q + 2];
            float q2 = __fadd_rn(__fadd_rn(__fmul_rn(qx, qx), __fmul_rn(qy, qy)),
                                 __fmul_rn(qz, qz));
            unsigned long long parked = 0;
#pragma unroll
            for (int j = 0; j < 64; ++j) {
                float Qx = bc_lane(qx, j), Qy = bc_lane(qy, j);
                float Qz = bc_lane(qz, j), Q2 = bc_lane(q2, j);
                float dot = __builtin_fmaf(Qz, dz,
                              __builtin_fmaf(Qy, dy, __fmul_rn(Qx, dx)));
                float uu = __fsub_rn(__fadd_rn(Q2, d2), __fmul_rn(2.0f, dot));
                unsigned long long mk = __ballot(uu <= T);
                if (lane == j) parked = mk;   // lane j keeps query qbase+j
            }
            // query-major store (1KB stride scatter; merges in L2)
            masks[(size_t)(qbase + lane) * 128 + c] = parked;
            atomicAdd(&counts[qbase + lane], __popcll(parked));
        }
    }
}

// Exclusive scan of counts[0..m) -> rs[0..m]. One block, m <= 8192. (Proven.)
__global__ __launch_bounds__(1024) void scan_kernel2(const int* __restrict__ counts,
                                                     int* __restrict__ rs, int m) {
    __shared__ int part[1024];
    int t = threadIdx.x;
    int base = t * 8;
    int c[8];
    int s = 0;
    for (int k = 0; k < 8; ++k) {
        int p = base + k;
        c[k] = (p < m) ? counts[p] : 0;
        s += c[k];
    }
    part[t] = s;
    __syncthreads();
    for (int off = 1; off < 1024; off <<= 1) {
        int v = 0;
        if (t >= off) v = part[t - off];
        __syncthreads();
        if (t >= off) part[t] += v;
        __syncthreads();
    }
    int run = (t == 0) ? 0 : part[t - 1];
    for (int k = 0; k < 8; ++k) {
        int p = base + k;
        if (p < m) rs[p] = run;
        run += c[k];
    }
    if (t == 1023) rs[m] = part[1023];
}

// Grid: 2048 x 256. R6-verbatim emit (query-major masks) + tail fill [L,C0).
__global__ __launch_bounds__(256) void emit_fill_tail(
    const unsigned long long* __restrict__ masks, const int* __restrict__ rs,
    int* __restrict__ out_idx) {
    int wave = threadIdx.x >> 6;
    int lane = threadIdx.x & 63;
    int q = blockIdx.x * 4 + wave;

    // ---- emit (positions < L) ----
    unsigned long long lo = masks[(size_t)q * 128 + lane];
    unsigned long long hi = masks[(size_t)q * 128 + 64 + lane];
    int plo = __popcll(lo), phi = __popcll(hi);
    int ilo = plo, ihi = phi;
    for (int off = 1; off < 64; off <<= 1) {
        int a = __shfl_up(ilo, off, 64);
        int b = __shfl_up(ihi, off, 64);
        if (lane >= off) { ilo += a; ihi += b; }
    }
    int total_lo = __shfl(ilo, 63, 64);
    int base = rs[q];
    int pos_lo = base + ilo - plo;
    int pos_hi = base + total_lo + ihi - phi;
    int jb_lo = lane * 64, jb_hi = (64 + lane) * 64;
    while (lo) {
        int b = __builtin_ctzll(lo);
        out_idx[pos_lo++] = jb_lo + b;
        lo &= lo - 1;
    }
    while (hi) {
        int b = __builtin_ctzll(hi);
        out_idx[pos_hi++] = jb_hi + b;
        hi &= hi - 1;
    }

    // ---- tail fill [L, C0) (K1 filled [C0, 64M)) ----
    int L = rs[N8];
    int Lr = (L + 3) & ~3;
    if (blockIdx.x == 0 && (int)threadIdx.x < (Lr - L))
        out_idx[L + threadIdx.x] = -1;
    int4* out4 = (int4*)out_idx;
    const int4 v = make_int4(-1, -1, -1, -1);
    const int c04 = C0 >> 2;
    int i = (Lr >> 2) + blockIdx.x * 256 + threadIdx.x;
    const int stride = 2048 * 256;
    for (; i < c04; i += stride) out4[i] = v;
}

// ====================== generic fallback (round-1 path) ======================

__global__ __launch_bounds__(256) void fill_kernel(int* __restrict__ out, size_t total) {
    size_t n4 = total >> 2;
    int4* out4 = (int4*)out;
    size_t i = (size_t)blockIdx.x * blockDim.x + threadIdx.x;
    size_t stride = (size_t)gridDim.x * blockDim.x;
    const int4 v = make_int4(-1, -1, -1, -1);
    for (; i < n4; i += stride) out4[i] = v;
    if (blockIdx.x == 0 && threadIdx.x == 0) {
        for (size_t k = n4 << 2; k < total; ++k) out[k] = -1;
    }
}

__global__ __launch_bounds__(256) void count_kernel(
    const float* __restrict__ data, const float* __restrict__ queries,
    const float* __restrict__ radius_p, int n, int m, int* __restrict__ counts) {
    int q = (blockIdx.x * blockDim.x + threadIdx.x) >> 6;
    int lane = threadIdx.x & 63;
    if (q >= m) return;
    float r = radius_p[0];
    float T = sq_threshold(r);
    float qx = queries[3 * q + 0], qy = queries[3 * q + 1], qz = queries[3 * q + 2];
    float q2 = __fadd_rn(__fadd_rn(__fmul_rn(qx, qx), __fmul_rn(qy, qy)),
                         __fmul_rn(qz, qz));
    int cnt = 0;
    for (int j = lane; j < n; j += 64) {
        float u = pair_metric(qx, qy, qz, q2, data[3 * j], data[3 * j + 1], data[3 * j + 2]);
        if (u <= T) cnt++;
    }
    for (int off = 32; off > 0; off >>= 1) cnt += __shfl_down(cnt, off, 64);
    if (lane == 0) counts[q] = cnt;
}

__global__ __launch_bounds__(256) void emit_kernel(
    const float* __restrict__ data, const float* __restrict__ queries,
    const float* __restrict__ radius_p, int n, int m,
    const int* __restrict__ row_splits, int* __restrict__ out_idx) {
    int q = (blockIdx.x * blockDim.x + threadIdx.x) >> 6;
    int lane = threadIdx.x & 63;
    if (q >= m) return;
    float r = radius_p[0];
    float T = sq_threshold(r);
    float qx = queries[3 * q + 0], qy = queries[3 * q + 1], qz = queries[3 * q + 2];
    float q2 = __fadd_rn(__fadd_rn(__fmul_rn(qx, qx), __fmul_rn(qy, qy)),
                         __fmul_rn(qz, qz));
    int base = row_splits[q];
    unsigned long long lane_mask_lt = (lane == 0) ? 0ULL : (~0ULL >> (64 - lane));
    for (int j0 = 0; j0 < n; j0 += 64) {
        int j = j0 + lane;
        bool pred = false;
        if (j < n) {
            float u = pair_metric(qx, qy, qz, q2, data[3 * j], data[3 * j + 1], data[3 * j + 2]);
            pred = (u <= T);
        }
        unsigned long long mask = __ballot(pred);
        if (pred) {
            int pos = base + __popcll(mask & lane_mask_lt);
            out_idx[pos] = j;
        }
        base += __popcll(mask);
    }
}

// ===========================================================================

extern "C" void kernel_launch(void* const* d_in, const int* in_sizes, int n_in,
                              void* d_out, int out_size, void* d_ws, size_t ws_size,
                              hipStream_t stream) {
    const float* data = (const float*)d_in[0];
    const float* queries = (const float*)d_in[1];
    const float* radius = (const float*)d_in[2];
    int n = in_sizes[0] / 3;
    int m = in_sizes[1] / 3;
    int* out = (int*)d_out;
    size_t idx_count = (size_t)m * (size_t)n;
    int* row = out + idx_count;  // m+1 ints

    // ws layout: masks (8MB, query-major) | counts (32KB)
    size_t mask_bytes = (size_t)N8 * 128 * 8;
    size_t need = mask_bytes + N8 * 4;
    bool fast = (n == N8) && (m == N8) && (ws_size >= need);

    if (fast) {
        unsigned long long* masks = (unsigned long long*)d_ws;
        int* counts = (int*)((char*)d_ws + mask_bytes);
        hipMemsetAsync(counts, 0, N8 * sizeof(int), stream);
        fused_fill_count<<<2048, 256, 0, stream>>>(data, queries, radius, out,
                                                   masks, counts);
        scan_kernel2<<<1, 1024, 0, stream>>>(counts, row, m);
        emit_fill_tail<<<2048, 256, 0, stream>>>(masks, row, out);
    } else {
        fill_kernel<<<2048, 256, 0, stream>>>(out, idx_count);
        int blocks = (m * 64 + 255) / 256;
        count_kernel<<<blocks, 256, 0, stream>>>(data, queries, radius, n, m, row);
        scan_kernel2<<<1, 1024, 0, stream>>>(row, row, m);
        emit_kernel<<<blocks, 256, 0, stream>>>(data, queries, radius, n, m, row, out);
    }
}

// Round 10
// 77.527 us; speedup vs baseline: 1.2209x; 1.1005x over previous
//
#include <hip/hip_runtime.h>
#include <stdint.h>

// ---------------------------------------------------------------------------
// NeighborSearch: data[n,3], queries[m,3], radius scalar.
// Out layout (int32): [0, m*n)   neighbors_index (compacted front, -1 pad)
//                     [m*n, m*n+m+1) row_splits (exclusive prefix of counts)
//
// Fast path (n==m==8192):
//   memset: counts = 0.
//   K1 count_then_fill (2048x256): PHASES, not roles (R2/R4/R9 lesson: any
//     half-machine fill runs at ~5.2 TB/s -- too few stores in flight).
//     Phase A (all blocks, ~4us): wave w = bid*4+wv owns unit u=w: chunk
//       c=u>>6 (64 points in regs), query group g=u&63. readlane broadcast,
//       ballot masks, query-major store, atomicAdd counts. (Proven R9.)
//     Phase B (all blocks): -1 int4 stream over [C0, 64M) -- full-machine
//       write regime, ~36us.
//   K2 scan (proven): counts -> row_splits.
//   K3 emit_fill_tail (proven R9): emit [0,L) + tail fill [L, C0).
// ---------------------------------------------------------------------------

#define N8 8192
#define C0 2097152  // fill boundary in ints (8 MB)

__device__ __forceinline__ float next_up(float x) {
    return __uint_as_float(__float_as_uint(x) + 1u);
}
__device__ __forceinline__ float next_down(float x) {
    return __uint_as_float(__float_as_uint(x) - 1u);
}

// Largest float T such that correctly-rounded sqrt(T) <= r (r > 0).
// (u <= T) <=> (sqrt_rn(max(u,0)) <= r), since sqrt_rn is monotone.
__device__ __forceinline__ float sq_threshold(float r) {
    float T = __fmul_rn(r, r);
    while (__fsqrt_rn(T) > r) T = next_down(T);
    while (__fsqrt_rn(next_up(T)) <= r) T = next_up(T);
    return T;
}

// Reference arithmetic, exactly (no contraction):
// d2 = (dx*dx + dy*dy) + dz*dz ; dot = fma(qz,dz, fma(qy,dy, qx*dx))
// u  = (q2 + d2) - 2*dot
__device__ __forceinline__ float pair_metric(float qx, float qy, float qz, float q2,
                                             float dx, float dy, float dz) {
    float d2 = __fadd_rn(__fadd_rn(__fmul_rn(dx, dx), __fmul_rn(dy, dy)),
                         __fmul_rn(dz, dz));
    float dot = __builtin_fmaf(qz, dz, __builtin_fmaf(qy, dy, __fmul_rn(qx, dx)));
    return __fsub_rn(__fadd_rn(q2, d2), __fmul_rn(2.0f, dot));
}

__device__ __forceinline__ float bc_lane(float x, int j) {
    return __int_as_float(__builtin_amdgcn_readlane(__float_as_int(x), j));
}

// ========================= fast path (8192 x 8192) =========================

// Grid: 2048 x 256. Phase A: count (1 unit per wave). Phase B: fill.
__global__ __launch_bounds__(256) void count_then_fill(
    const float* __restrict__ data, const float* __restrict__ queries,
    const float* __restrict__ radius_p, int* __restrict__ out_idx,
    unsigned long long* __restrict__ masks, int* __restrict__ counts) {
    int bid = blockIdx.x;
    int lane = threadIdx.x & 63;
    int wv = threadIdx.x >> 6;

    // ---- Phase A: count (unit u = bid*4 + wv) ----
    {
        int u = bid * 4 + wv;
        int c = u >> 6;          // data chunk 0..127
        int g = u & 63;          // query group 0..63
        float T = sq_threshold(radius_p[0]);
        int p = c * 64 + lane;
        float dx = data[3 * p + 0], dy = data[3 * p + 1], dz = data[3 * p + 2];
        float d2 = __fadd_rn(__fadd_rn(__fmul_rn(dx, dx), __fmul_rn(dy, dy)),
                             __fmul_rn(dz, dz));
        for (int s = 0; s < 2; ++s) {
            int qbase = g * 128 + s * 64;
            int q = qbase + lane;
            float qx = queries[3 * q + 0], qy = queries[3 * q + 1],
                  qz = queries[3 * q + 2];
            float q2 = __fadd_rn(__fadd_rn(__fmul_rn(qx, qx), __fmul_rn(qy, qy)),
                                 __fmul_rn(qz, qz));
            unsigned long long parked = 0;
#pragma unroll
            for (int j = 0; j < 64; ++j) {
                float Qx = bc_lane(qx, j), Qy = bc_lane(qy, j);
                float Qz = bc_lane(qz, j), Q2 = bc_lane(q2, j);
                float dot = __builtin_fmaf(Qz, dz,
                              __builtin_fmaf(Qy, dy, __fmul_rn(Qx, dx)));
                float uu = __fsub_rn(__fadd_rn(Q2, d2), __fmul_rn(2.0f, dot));
                unsigned long long mk = __ballot(uu <= T);
                if (lane == j) parked = mk;   // lane j keeps query qbase+j
            }
            masks[(size_t)(qbase + lane) * 128 + c] = parked;  // query-major
            atomicAdd(&counts[qbase + lane], __popcll(parked));
        }
    }

    // ---- Phase B: fill [C0, 64M) with -1 (full machine) ----
    int4* out4 = (int4*)out_idx;
    const int4 v = make_int4(-1, -1, -1, -1);
    const size_t n4 = (size_t)N8 * N8 / 4;
    size_t i = (size_t)(C0 / 4) + (size_t)bid * 256 + threadIdx.x;
    const size_t stride = 2048ull * 256ull;
    for (; i < n4; i += stride) out4[i] = v;
}

// Exclusive scan of counts[0..m) -> rs[0..m]. One block, m <= 8192. (Proven.)
__global__ __launch_bounds__(1024) void scan_kernel2(const int* __restrict__ counts,
                                                     int* __restrict__ rs, int m) {
    __shared__ int part[1024];
    int t = threadIdx.x;
    int base = t * 8;
    int c[8];
    int s = 0;
    for (int k = 0; k < 8; ++k) {
        int p = base + k;
        c[k] = (p < m) ? counts[p] : 0;
        s += c[k];
    }
    part[t] = s;
    __syncthreads();
    for (int off = 1; off < 1024; off <<= 1) {
        int v = 0;
        if (t >= off) v = part[t - off];
        __syncthreads();
        if (t >= off) part[t] += v;
        __syncthreads();
    }
    int run = (t == 0) ? 0 : part[t - 1];
    for (int k = 0; k < 8; ++k) {
        int p = base + k;
        if (p < m) rs[p] = run;
        run += c[k];
    }
    if (t == 1023) rs[m] = part[1023];
}

// Grid: 2048 x 256. Proven R9: emit [0,L) from query-major masks + fill [L,C0).
__global__ __launch_bounds__(256) void emit_fill_tail(
    const unsigned long long* __restrict__ masks, const int* __restrict__ rs,
    int* __restrict__ out_idx) {
    int wave = threadIdx.x >> 6;
    int lane = threadIdx.x & 63;
    int q = blockIdx.x * 4 + wave;

    // ---- emit (positions < L) ----
    unsigned long long lo = masks[(size_t)q * 128 + lane];
    unsigned long long hi = masks[(size_t)q * 128 + 64 + lane];
    int plo = __popcll(lo), phi = __popcll(hi);
    int ilo = plo, ihi = phi;
    for (int off = 1; off < 64; off <<= 1) {
        int a = __shfl_up(ilo, off, 64);
        int b = __shfl_up(ihi, off, 64);
        if (lane >= off) { ilo += a; ihi += b; }
    }
    int total_lo = __shfl(ilo, 63, 64);
    int base = rs[q];
    int pos_lo = base + ilo - plo;
    int pos_hi = base + total_lo + ihi - phi;
    int jb_lo = lane * 64, jb_hi = (64 + lane) * 64;
    while (lo) {
        int b = __builtin_ctzll(lo);
        out_idx[pos_lo++] = jb_lo + b;
        lo &= lo - 1;
    }
    while (hi) {
        int b = __builtin_ctzll(hi);
        out_idx[pos_hi++] = jb_hi + b;
        hi &= hi - 1;
    }

    // ---- tail fill [L, C0) (K1 filled [C0, 64M)) ----
    int L = rs[N8];
    int Lr = (L + 3) & ~3;
    if (blockIdx.x == 0 && (int)threadIdx.x < (Lr - L))
        out_idx[L + threadIdx.x] = -1;
    int4* out4 = (int4*)out_idx;
    const int4 v = make_int4(-1, -1, -1, -1);
    const int c04 = C0 >> 2;
    int i = (Lr >> 2) + blockIdx.x * 256 + threadIdx.x;
    const int stride = 2048 * 256;
    for (; i < c04; i += stride) out4[i] = v;
}

// ====================== generic fallback (round-1 path) ======================

__global__ __launch_bounds__(256) void fill_kernel(int* __restrict__ out, size_t total) {
    size_t n4 = total >> 2;
    int4* out4 = (int4*)out;
    size_t i = (size_t)blockIdx.x * blockDim.x + threadIdx.x;
    size_t stride = (size_t)gridDim.x * blockDim.x;
    const int4 v = make_int4(-1, -1, -1, -1);
    for (; i < n4; i += stride) out4[i] = v;
    if (blockIdx.x == 0 && threadIdx.x == 0) {
        for (size_t k = n4 << 2; k < total; ++k) out[k] = -1;
    }
}

__global__ __launch_bounds__(256) void count_kernel(
    const float* __restrict__ data, const float* __restrict__ queries,
    const float* __restrict__ radius_p, int n, int m, int* __restrict__ counts) {
    int q = (blockIdx.x * blockDim.x + threadIdx.x) >> 6;
    int lane = threadIdx.x & 63;
    if (q >= m) return;
    float r = radius_p[0];
    float T = sq_threshold(r);
    float qx = queries[3 * q + 0], qy = queries[3 * q + 1], qz = queries[3 * q + 2];
    float q2 = __fadd_rn(__fadd_rn(__fmul_rn(qx, qx), __fmul_rn(qy, qy)),
                         __fmul_rn(qz, qz));
    int cnt = 0;
    for (int j = lane; j < n; j += 64) {
        float u = pair_metric(qx, qy, qz, q2, data[3 * j], data[3 * j + 1], data[3 * j + 2]);
        if (u <= T) cnt++;
    }
    for (int off = 32; off > 0; off >>= 1) cnt += __shfl_down(cnt, off, 64);
    if (lane == 0) counts[q] = cnt;
}

__global__ __launch_bounds__(256) void emit_kernel(
    const float* __restrict__ data, const float* __restrict__ queries,
    const float* __restrict__ radius_p, int n, int m,
    const int* __restrict__ row_splits, int* __restrict__ out_idx) {
    int q = (blockIdx.x * blockDim.x + threadIdx.x) >> 6;
    int lane = threadIdx.x & 63;
    if (q >= m) return;
    float r = radius_p[0];
    float T = sq_threshold(r);
    float qx = queries[3 * q + 0], qy = queries[3 * q + 1], qz = queries[3 * q + 2];
    float q2 = __fadd_rn(__fadd_rn(__fmul_rn(qx, qx), __fmul_rn(qy, qy)),
                         __fmul_rn(qz, qz));
    int base = row_splits[q];
    unsigned long long lane_mask_lt = (lane == 0) ? 0ULL : (~0ULL >> (64 - lane));
    for (int j0 = 0; j0 < n; j0 += 64) {
        int j = j0 + lane;
        bool pred = false;
        if (j < n) {
            float u = pair_metric(qx, qy, qz, q2, data[3 * j], data[3 * j + 1], data[3 * j + 2]);
            pred = (u <= T);
        }
        unsigned long long mask = __ballot(pred);
        if (pred) {
            int pos = base + __popcll(mask & lane_mask_lt);
            out_idx[pos] = j;
        }
        base += __popcll(mask);
    }
}

// ===========================================================================

extern "C" void kernel_launch(void* const* d_in, const int* in_sizes, int n_in,
                              void* d_out, int out_size, void* d_ws, size_t ws_size,
                              hipStream_t stream) {
    const float* data = (const float*)d_in[0];
    const float* queries = (const float*)d_in[1];
    const float* radius = (const float*)d_in[2];
    int n = in_sizes[0] / 3;
    int m = in_sizes[1] / 3;
    int* out = (int*)d_out;
    size_t idx_count = (size_t)m * (size_t)n;
    int* row = out + idx_count;  // m+1 ints

    // ws layout: masks (8MB, query-major) | counts (32KB)
    size_t mask_bytes = (size_t)N8 * 128 * 8;
    size_t need = mask_bytes + N8 * 4;
    bool fast = (n == N8) && (m == N8) && (ws_size >= need);

    if (fast) {
        unsigned long long* masks = (unsigned long long*)d_ws;
        int* counts = (int*)((char*)d_ws + mask_bytes);
        hipMemsetAsync(counts, 0, N8 * sizeof(int), stream);
        count_then_fill<<<2048, 256, 0, stream>>>(data, queries, radius, out,
                                                  masks, counts);
        scan_kernel2<<<1, 1024, 0, stream>>>(counts, row, m);
        emit_fill_tail<<<2048, 256, 0, stream>>>(masks, row, out);
    } else {
        fill_kernel<<<2048, 256, 0, stream>>>(out, idx_count);
        int blocks = (m * 64 + 255) / 256;
        count_kernel<<<blocks, 256, 0, stream>>>(data, queries, radius, n, m, row);
        scan_kernel2<<<1, 1024, 0, stream>>>(row, row, m);
        emit_kernel<<<blocks, 256, 0, stream>>>(data, queries, radius, n, m, row, out);
    }
}